// Round 1
// baseline (89.611 us; speedup 1.0000x reference)
//
#include <hip/hip_runtime.h>

// Problem constants (fixed by setup_inputs / FRAME_INTERVAL=10):
//   true_frames, predicted_frames: (B=128, T=1024, D=64) fp32
//   sample times t = 0,10,...,1020  -> S=103 integer knots -> dx==0
//   => loss == mean((true[b,t,d]-pred[b,t,d])^2) over sampled t.
#define BB 128
#define TT 1024
#define DD 64
#define SS 103
#define STRIDE 10
#define ROWS (BB * SS)          // 13184 (b,t) rows
#define V_PER_ROW (DD / 4)      // 16 float4 per row
#define TOTV (ROWS * V_PER_ROW) // 210944 float4 pairs
#define NPART 256               // blocks in pass 1

__global__ __launch_bounds__(256) void spline_mse_partial(
    const float4* __restrict__ yt, const float4* __restrict__ yp,
    double* __restrict__ part) {
  double acc = 0.0;
  const int nthreads = gridDim.x * blockDim.x;
  for (int g = blockIdx.x * blockDim.x + threadIdx.x; g < TOTV; g += nthreads) {
    const int v = g & (V_PER_ROW - 1);   // float4 index within D
    const int r = g >> 4;                // row index: r = s*128 + b
    const int b = r & (BB - 1);
    const int s = r >> 7;
    const int t = s * STRIDE;
    const int base = (b * TT + t) * V_PER_ROW + v;  // float4 offset into (B,T,D)
    const float4 a = yt[base];
    const float4 c = yp[base];
    const float d0 = a.x - c.x, d1 = a.y - c.y, d2 = a.z - c.z, d3 = a.w - c.w;
    acc += (double)(d0 * d0) + (double)(d1 * d1) +
           (double)(d2 * d2) + (double)(d3 * d3);
  }
  // wave (64-lane) reduction
  #pragma unroll
  for (int off = 32; off > 0; off >>= 1) acc += __shfl_down(acc, off, 64);
  __shared__ double sh[4];  // 256 threads = 4 waves
  const int lane = threadIdx.x & 63;
  const int wid = threadIdx.x >> 6;
  if (lane == 0) sh[wid] = acc;
  __syncthreads();
  if (threadIdx.x == 0) {
    part[blockIdx.x] = sh[0] + sh[1] + sh[2] + sh[3];
  }
}

__global__ __launch_bounds__(256) void spline_mse_finalize(
    const double* __restrict__ part, float* __restrict__ out) {
  double acc = (threadIdx.x < NPART) ? part[threadIdx.x] : 0.0;
  #pragma unroll
  for (int off = 32; off > 0; off >>= 1) acc += __shfl_down(acc, off, 64);
  __shared__ double sh[4];
  const int lane = threadIdx.x & 63;
  const int wid = threadIdx.x >> 6;
  if (lane == 0) sh[wid] = acc;
  __syncthreads();
  if (threadIdx.x == 0) {
    const double total = sh[0] + sh[1] + sh[2] + sh[3];
    const double denom = (double)SS * (double)BB * (double)DD;  // 843776
    out[0] = (float)(total / denom);
  }
}

extern "C" void kernel_launch(void* const* d_in, const int* in_sizes, int n_in,
                              void* d_out, int out_size, void* d_ws, size_t ws_size,
                              hipStream_t stream) {
  const float4* yt = (const float4*)d_in[0];
  const float4* yp = (const float4*)d_in[1];
  double* part = (double*)d_ws;          // NPART * 8 bytes of scratch
  float* out = (float*)d_out;

  spline_mse_partial<<<NPART, 256, 0, stream>>>(yt, yp, part);
  spline_mse_finalize<<<1, 256, 0, stream>>>(part, out);
}